// Round 1
// baseline (462.179 us; speedup 1.0000x reference)
//
#include <hip/hip_runtime.h>
#include <math.h>

#define NN   1024
#define DIN_ 128
#define DD   32
#define EE   32768

__device__ __forceinline__ float artanh_f(float x){
    x = fminf(fmaxf(x, -1.f + 1e-7f), 1.f - 1e-7f);
    return 0.5f * (log1pf(x) - log1pf(-x));
}
__device__ __forceinline__ float arcosh_f(float x){
    x = fmaxf(x, 1.f + 1e-7f);
    return logf(x + sqrtf(x*x - 1.f));
}

template<int D>
__device__ __forceinline__ void logmap0_t(const float* __restrict__ x, float* __restrict__ r){
    float ss = 0.f;
#pragma unroll
    for (int t=1; t<D; ++t) ss += x[t]*x[t];
    float yn = sqrtf(fmaxf(ss, 1e-15f));
    float s = arcosh_f(x[0]) / yn;
    r[0] = 0.f;
#pragma unroll
    for (int t=1; t<D; ++t) r[t] = s * x[t];
}

template<int D>
__device__ __forceinline__ void expmap0_proj_t(const float* __restrict__ u, float* __restrict__ out){
    float ss = 0.f;
#pragma unroll
    for (int t=1; t<D; ++t) ss += u[t]*u[t];
    float xn = sqrtf(fmaxf(ss, 1e-15f));
    float sh = sinhf(xn) / xn;
    float ys = 0.f;
#pragma unroll
    for (int t=1; t<D; ++t){ float o = sh*u[t]; out[t]=o; ys += o*o; }
    out[0] = sqrtf(fmaxf(1.f + ys, 1e-7f));
}

// out = h_proj(h_mobius_add(x, y)) for 32-dim hyperboloid points
__device__ __forceinline__ void mobius_add_proj32(const float* __restrict__ x, const float* __restrict__ y, float* __restrict__ out){
    float u[DD];
    logmap0_t<DD>(y, u);                      // u = logmap0(y), u[0]=0
    float ss = 0.f;
#pragma unroll
    for (int t=1; t<DD; ++t) ss += x[t]*x[t];
    float xn = sqrtf(fmaxf(ss, 1e-15f));      // snorm(x[1:])
    float alpha = 0.f;
#pragma unroll
    for (int t=1; t<DD; ++t) alpha += x[t]*u[t];
    alpha /= xn;                              // sum(yu*u[1:]) ; sqrtK=1
    float coef = alpha * (1.f - x[0]) / xn;   // alpha*(sqrtK - x0)/xn
    float w[DD];
#pragma unroll
    for (int t=1; t<DD; ++t) w[t] = u[t] - coef*x[t];
    float ux = 0.f;
#pragma unroll
    for (int t=1; t<DD; ++t) ux += x[t]*w[t];
    float w0 = ux / fmaxf(x[0], 1e-7f);       // proj_tan component 0
    float wsq = 0.f;
#pragma unroll
    for (int t=1; t<DD; ++t) wsq += w[t]*w[t];
    float nu = sqrtf(fmaxf(wsq - w0*w0, 1e-15f));
    float th = fmaxf(nu, 1e-15f);
    float ch = coshf(th), shq = sinhf(th)/th;
    float ys = 0.f;
#pragma unroll
    for (int t=1; t<DD; ++t){ float o = ch*x[t] + shq*w[t]; out[t]=o; ys += o*o; }
    out[0] = sqrtf(fmaxf(1.f + ys, 1e-7f));   // proj (idempotent vs outer proj)
}

// per-node: in_emb = hyp_linear(x, Wd, bd); p_in-derived lam*p_in and lam-1
__global__ void k_node(const float* __restrict__ x, const float* __restrict__ Wd,
                       const float* __restrict__ bd,
                       float* __restrict__ in_emb, float* __restrict__ lamp,
                       float* __restrict__ lam1){
    int i = blockIdx.x*blockDim.x + threadIdx.x;
    if (i >= NN) return;
    const float* xi = x + (size_t)i*DIN_;
    float x0 = xi[0];
    float ss = 0.f;
    for (int d=1; d<DIN_; ++d){ float t=xi[d]; ss += t*t; }
    float yn = sqrtf(fmaxf(ss, 1e-15f));
    float scale = arcosh_f(x0)/yn;            // logmap0 scale, u[d]=scale*xi[d], u[0]=0
    float v[DD]; v[0]=0.f;
    for (int k=1; k<DD; ++k){
        const float* wr = Wd + (size_t)k*DIN_;
        float acc=0.f;
        for (int d=1; d<DIN_; ++d) acc += wr[d]*xi[d];
        v[k] = acc*scale;
    }
    float res[DD]; expmap0_proj_t<DD>(v,res);
    float bt[DD]; bt[0]=0.f;
#pragma unroll
    for (int k=1;k<DD;++k) bt[k]=bd[k];
    float hb[DD]; expmap0_proj_t<DD>(bt,hb);  // hb = h_expmap0(bt)
    float o[DD]; mobius_add_proj32(res,hb,o);
#pragma unroll
    for (int k=0;k<DD;++k) in_emb[i*DD+k]=o[k];
    float sq=0.f; float p[DD-1];
#pragma unroll
    for (int t=0;t<DD-1;++t){ p[t]=o[1+t]/(o[0]+1.f); sq+=p[t]*p[t]; }  // to_poincare
    float lam = 2.f/fmaxf(1.f-sq, 1e-15f);
#pragma unroll
    for (int t=0;t<DD-1;++t) lamp[i*DD+t]=lam*p[t];
    lam1[i]=lam-1.f;
}

// per-edge: logits s[e][1..31] of the pre-softmax activation; claim cell slot
__global__ void k_edge_s(const int* __restrict__ edges, const float* __restrict__ Wa,
                         const float* __restrict__ in_emb,
                         float* __restrict__ sbuf, int* __restrict__ slotmap){
    int e = blockIdx.x*blockDim.x + threadIdx.x;
    if (e >= EE) return;
    int i = edges[e], j = edges[EE+e];
    const float* A = in_emb + i*DD;
    const float* B = in_emb + j*DD;
    float cat[2*(DD-1)];
    float a0 = A[0]+1.f, b0 = B[0]+1.f;
    float sq = 0.f;
#pragma unroll
    for (int t=0;t<DD-1;++t){ float p=A[1+t]/a0; cat[t]=p; sq+=p*p; }        // tgt
#pragma unroll
    for (int t=0;t<DD-1;++t){ float p=B[1+t]/b0; cat[DD-1+t]=p; sq+=p*p; }   // src
    float dnm = fmaxf(1.f-sq, 1e-15f);        // from_poincare denom
    float c0 = (1.f+sq)/dnm;
    float ssy = 0.f;
#pragma unroll
    for (int t=0;t<2*(DD-1);++t){ float yv=2.f*cat[t]/dnm; cat[t]=yv; ssy += yv*yv; }
    float ynn = sqrtf(fmaxf(ssy,1e-15f));
    float sc2 = arcosh_f(c0)/ynn;             // logmap0 scale for the 63-dim point
    float v[DD]; v[0]=0.f;
    for (int k=1;k<DD;++k){
        const float* wr = Wa + k*(2*DD-1);
        float acc=0.f;
#pragma unroll
        for (int t=0;t<2*(DD-1);++t) acc += wr[1+t]*cat[t];
        v[k]=acc*sc2;
    }
    float res[DD]; expmap0_proj_t<DD>(v,res);
    float r[DD]; logmap0_t<DD>(res,r);
#pragma unroll
    for (int t=1;t<DD;++t) r[t] = r[t]>=0.f ? r[t] : 0.2f*r[t];   // leaky_relu act
    float res2[DD]; expmap0_proj_t<DD>(r,res2);
    float sarr[DD]; logmap0_t<DD>(res2,sarr);
#pragma unroll
    for (int t=1;t<DD;++t) sbuf[e*DD+t]=sarr[t];
    atomicMax(&slotmap[i*NN+j], e);           // deterministic winner = max edge id
}

// one block per column t=1..31: global max then sum of exp
__global__ void k_colreduce(const float* __restrict__ sbuf,
                            float* __restrict__ colmax, float* __restrict__ colsum){
    int t = blockIdx.x + 1;
    __shared__ float red[256];
    int tid = threadIdx.x;
    float mx = -3.4e38f;
    for (int e=tid; e<EE; e+=256) mx = fmaxf(mx, sbuf[e*DD+t]);
    red[tid]=mx; __syncthreads();
    for (int off=128; off>0; off>>=1){
        if (tid<off) red[tid]=fmaxf(red[tid],red[tid+off]);
        __syncthreads();
    }
    float cm = red[0]; __syncthreads();
    float sm = 0.f;
    for (int e=tid; e<EE; e+=256) sm += expf(sbuf[e*DD+t]-cm);
    red[tid]=sm; __syncthreads();
    for (int off=128; off>0; off>>=1){
        if (tid<off) red[tid]+=red[tid+off];
        __syncthreads();
    }
    if (tid==0){ colmax[t]=cm; colsum[t]=red[0]; }
}

// per-edge: softmax -> a = proj(expmap0([0,p])); accumulate per-cell sums
__global__ void k_edge_a(const int* __restrict__ edges, const float* __restrict__ sbuf,
                         const float* __restrict__ colmax, const float* __restrict__ colsum,
                         const int* __restrict__ slotmap,
                         float* __restrict__ asum, int* __restrict__ count){
    int e = blockIdx.x*blockDim.x + threadIdx.x;
    if (e >= EE) return;
    float u[DD]; u[0]=0.f;
#pragma unroll
    for (int t=1;t<DD;++t) u[t] = expf(sbuf[e*DD+t]-colmax[t]) / colsum[t];
    float a[DD]; expmap0_proj_t<DD>(u,a);
    int i = edges[e], j = edges[EE+e];
    int slot = slotmap[i*NN+j];
    atomicAdd(&count[slot],1);
#pragma unroll
    for (int k=0;k<DD;++k) atomicAdd(&asum[slot*DD+k], a[k]);
}

// per unique cell (winner edge): att value, accumulate num/den rows
__global__ void k_cell(const int* __restrict__ edges, const int* __restrict__ slotmap,
                       const int* __restrict__ count, const float* __restrict__ asum,
                       const float* __restrict__ in_emb, const float* __restrict__ lamp,
                       const float* __restrict__ lam1,
                       float* __restrict__ numb, float* __restrict__ denb){
    int e = blockIdx.x*blockDim.x + threadIdx.x;
    if (e >= EE) return;
    int i = edges[e], j = edges[EE+e];
    if (slotmap[i*NN+j] != e) return;         // only the winner processes the cell
    float m = (float)count[e];                // mask multiplicity
    const float* ac = asum + e*DD;            // a_dense cell (sum over duplicates)
    const float* w  = in_emb + j*DD;          // w_masked cell = m * in_emb[j]
    float ad = ac[0]+1.f;
    float wd = m*w[0]+1.f;
    float dot=0.f, wns=0.f;
#pragma unroll
    for (int t=1;t<DD;++t){
        float pa = ac[t]/ad;
        float pw = m*w[t]/wd;
        dot += pa*pw; wns += pw*pw;
    }
    float wn = sqrtf(fmaxf(wns,1e-15f));
    float att = tanhf(dot/wn * artanh_f(wn));
#pragma unroll
    for (int t=0;t<DD-1;++t) atomicAdd(&numb[i*DD+t], att*lamp[j*DD+t]);
    atomicAdd(&denb[i], att*lam1[j]);
}

// per-node epilogue: g -> p_out -> from_poincare -> hyp_linear(Wo, bo)
__global__ void k_out(const float* __restrict__ numb, const float* __restrict__ denb,
                      const float* __restrict__ Wo, const float* __restrict__ bo,
                      float* __restrict__ out){
    int i = blockIdx.x*blockDim.x + threadIdx.x;
    if (i >= NN) return;
    float dn = denb[i];
    if (fabsf(dn) < 1e-10f) dn = 1e-10f;
    float g[DD-1]; float gss=0.f;
#pragma unroll
    for (int t=0;t<DD-1;++t){ g[t]=numb[i*DD+t]/dn; gss+=g[t]*g[t]; }
    float gn = sqrtf(fmaxf(gss,1e-15f));
    float scl = tanhf(0.5f*artanh_f(gn))/gn;
    float sq=0.f;
#pragma unroll
    for (int t=0;t<DD-1;++t){ g[t]*=scl; sq+=g[t]*g[t]; }   // g is now p_out
    float dnm = fmaxf(1.f-sq, 1e-15f);
    float h[DD];
    h[0]=(1.f+sq)/dnm;
#pragma unroll
    for (int t=0;t<DD-1;++t) h[1+t]=2.f*g[t]/dnm;           // h_from_poincare
    float r[DD]; logmap0_t<DD>(h,r);
    float v[DD]; v[0]=0.f;
    for (int k=1;k<DD;++k){
        const float* wr = Wo + k*DD;
        float acc=0.f;
#pragma unroll
        for (int d=1;d<DD;++d) acc += wr[d]*r[d];
        v[k]=acc;
    }
    float res[DD]; expmap0_proj_t<DD>(v,res);
    float bt[DD]; bt[0]=0.f;
#pragma unroll
    for (int k=1;k<DD;++k) bt[k]=bo[k];
    float hb[DD]; expmap0_proj_t<DD>(bt,hb);
    float o[DD]; mobius_add_proj32(res,hb,o);
#pragma unroll
    for (int k=0;k<DD;++k) out[i*DD+k]=o[k];
}

extern "C" void kernel_launch(void* const* d_in, const int* in_sizes, int n_in,
                              void* d_out, int out_size, void* d_ws, size_t ws_size,
                              hipStream_t stream) {
    const float* x  = (const float*)d_in[0];
    const int* edges = (const int*)d_in[1];
    const float* Wd = (const float*)d_in[2];
    const float* bd = (const float*)d_in[3];
    const float* Wa = (const float*)d_in[4];
    const float* Wo = (const float*)d_in[5];
    const float* bo = (const float*)d_in[6];
    float* out = (float*)d_out;

    // workspace layout (~13 MB)
    float* f       = (float*)d_ws;
    float* in_emb  = f;                      // NN*DD
    float* lamp    = in_emb + NN*DD;         // NN*DD (31 used/row)
    float* lam1    = lamp   + NN*DD;         // NN
    float* sbuf    = lam1   + NN;            // EE*DD (cols 1..31 used)
    float* asum    = sbuf   + (size_t)EE*DD; // EE*DD
    float* numb    = asum   + (size_t)EE*DD; // NN*DD (31 used/row)
    float* denb    = numb   + NN*DD;         // NN
    float* colmax  = denb   + NN;            // DD
    float* colsum  = colmax + DD;            // DD
    int*   slotmap = (int*)(colsum + DD);    // NN*NN
    int*   count   = slotmap + (size_t)NN*NN;// EE

    hipMemsetAsync(slotmap, 0xFF, (size_t)NN*NN*sizeof(int), stream);   // -1
    hipMemsetAsync(asum,    0,    (size_t)EE*DD*sizeof(float), stream);
    hipMemsetAsync(count,   0,    (size_t)EE*sizeof(int), stream);
    hipMemsetAsync(numb,    0,    (size_t)NN*DD*sizeof(float), stream);
    hipMemsetAsync(denb,    0,    (size_t)NN*sizeof(float), stream);

    k_node<<<NN/256, 256, 0, stream>>>(x, Wd, bd, in_emb, lamp, lam1);
    k_edge_s<<<EE/256, 256, 0, stream>>>(edges, Wa, in_emb, sbuf, slotmap);
    k_colreduce<<<DD-1, 256, 0, stream>>>(sbuf, colmax, colsum);
    k_edge_a<<<EE/256, 256, 0, stream>>>(edges, sbuf, colmax, colsum, slotmap, asum, count);
    k_cell<<<EE/256, 256, 0, stream>>>(edges, slotmap, count, asum, in_emb, lamp, lam1, numb, denb);
    k_out<<<NN/256, 256, 0, stream>>>(numb, denb, Wo, bo, out);
}

// Round 2
// 116.122 us; speedup vs baseline: 3.9801x; 3.9801x over previous
//
#include <hip/hip_runtime.h>
#include <math.h>

#define NN   1024
#define DIN_ 128
#define DD   32
#define EE   32768

__device__ __forceinline__ float artanh_f(float x){
    x = fminf(fmaxf(x, -1.f + 1e-7f), 1.f - 1e-7f);
    return 0.5f * (log1pf(x) - log1pf(-x));
}
__device__ __forceinline__ float arcosh_f(float x){
    x = fmaxf(x, 1.f + 1e-7f);
    return logf(x + sqrtf(x*x - 1.f));
}

// butterfly sum over a 32-lane group (result identical on all lanes)
__device__ __forceinline__ float rsum(float v){
#pragma unroll
    for (int off=16; off>0; off>>=1) v += __shfl_xor(v, off, 32);
    return v;
}

// lane-parallel: each lane holds component [lane] of a 32-dim vector.
__device__ __forceinline__ float logmap0_l(float xv, int lane){
    float ss = rsum(lane>=1 ? xv*xv : 0.f);
    float yn = sqrtf(fmaxf(ss, 1e-15f));
    float x0 = __shfl(xv, 0, 32);
    float s  = arcosh_f(x0) / yn;
    return lane>=1 ? s*xv : 0.f;
}

__device__ __forceinline__ float expmap0_proj_l(float uv, int lane){
    float ss = rsum(lane>=1 ? uv*uv : 0.f);
    float xn = sqrtf(fmaxf(ss, 1e-15f));
    float sh = sinhf(xn)/xn;
    float o  = sh*uv;                       // lanes>=1
    float ys = rsum(lane>=1 ? o*o : 0.f);
    float o0 = sqrtf(fmaxf(1.f+ys, 1e-7f));
    return lane==0 ? o0 : o;
}

// h_proj(h_mobius_add(x, y)) lane-parallel
__device__ __forceinline__ float mobius_add_proj_l(float xv, float yv, int lane){
    float u  = logmap0_l(yv, lane);         // u[0]=0
    float x1 = lane>=1 ? xv : 0.f;
    float ss = rsum(x1*x1);
    float xn = sqrtf(fmaxf(ss, 1e-15f));
    float alpha = rsum(x1*u) / xn;
    float x0 = __shfl(xv, 0, 32);
    float coef = alpha * (1.f - x0) / xn;
    float w  = lane>=1 ? u - coef*xv : 0.f;
    float ux = rsum(x1*w);
    float w0 = ux / fmaxf(x0, 1e-7f);
    float wsq = rsum(w*w);
    float nu = sqrtf(fmaxf(wsq - w0*w0, 1e-15f));
    float th = fmaxf(nu, 1e-15f);
    float ch = coshf(th), shq = sinhf(th)/th;
    float o  = ch*xv + shq*w;               // lanes>=1
    float ys = rsum(lane>=1 ? o*o : 0.f);
    float o0 = sqrtf(fmaxf(1.f+ys, 1e-7f));
    return lane==0 ? o0 : o;
}

// per-node: in_emb = hyp_linear(x, Wd, bd); lamp row = [lam-1, lam*p_1..31]
__global__ __launch_bounds__(256) void k_node(const float* __restrict__ x,
        const float* __restrict__ Wd, const float* __restrict__ bd,
        float* __restrict__ in_emb, float* __restrict__ lamp){
    __shared__ float xs[8][128];
    __shared__ float Wd_s[32][129];
    int tid = threadIdx.x, lane = tid&31, grp = tid>>5;
    int node = blockIdx.x*8 + grp;
    for (int idx=tid; idx<32*128; idx+=256) Wd_s[idx>>7][idx&127] = Wd[idx];
#pragma unroll
    for (int r=0;r<4;++r) xs[grp][lane+32*r] = x[node*128 + lane + 32*r];
    __syncthreads();
    float ssp = 0.f;
#pragma unroll
    for (int r=0;r<4;++r){ int d=lane+32*r; float t=xs[grp][d]; if (d>=1) ssp += t*t; }
    float ss = rsum(ssp);
    float yn = sqrtf(fmaxf(ss, 1e-15f));
    float x0 = xs[grp][0];
    float scale = arcosh_f(x0)/yn;          // logmap0 scale
    float acc = 0.f;
    for (int d=1; d<128; ++d) acc += Wd_s[lane][d]*xs[grp][d];
    float v = lane>=1 ? acc*scale : 0.f;
    float res = expmap0_proj_l(v, lane);
    float bt  = lane>=1 ? bd[lane] : 0.f;
    float hb  = expmap0_proj_l(bt, lane);
    float o   = mobius_add_proj_l(res, hb, lane);
    in_emb[node*32+lane] = o;
    float o0 = __shfl(o, 0, 32);
    float p  = lane>=1 ? o/(o0+1.f) : 0.f;  // to_poincare
    float sq = rsum(p*p);
    float lam = 2.f/fmaxf(1.f-sq, 1e-15f);
    lamp[node*32+lane] = lane>=1 ? lam*p : lam-1.f;
}

// per-edge: logits s[e][1..31]; claim cell slot
__global__ __launch_bounds__(256) void k_edge_s(const int* __restrict__ edges,
        const float* __restrict__ Wa, const float* __restrict__ in_emb,
        float* __restrict__ sbuf, int* __restrict__ slotmap){
    __shared__ float Wa_s[32*65];
    __shared__ float cat_s[8][64];
    int tid = threadIdx.x, lane = tid&31, grp = tid>>5;
    int e = blockIdx.x*8 + grp;
    for (int idx=tid; idx<32*63; idx+=256){ int k=idx/63, c=idx-63*k; Wa_s[k*65+c]=Wa[idx]; }
    int i = edges[e], j = edges[EE+e];
    float A = in_emb[i*32+lane], B = in_emb[j*32+lane];
    float a0 = __shfl(A,0,32)+1.f, b0 = __shfl(B,0,32)+1.f;
    float pa = lane>=1 ? A/a0 : 0.f;        // tgt poincare
    float pb = lane>=1 ? B/b0 : 0.f;        // src poincare
    float sq = rsum(pa*pa + pb*pb);
    float dnm = fmaxf(1.f-sq, 1e-15f);      // from_poincare denom
    float c0  = (1.f+sq)/dnm;
    float ya = 2.f*pa/dnm, yb = 2.f*pb/dnm;
    float ssy = rsum(ya*ya + yb*yb);
    float ynn = sqrtf(fmaxf(ssy, 1e-15f));
    float sc2 = arcosh_f(c0)/ynn;           // logmap0 scale (63-dim point)
    if (lane>=1){ cat_s[grp][lane-1]=ya; cat_s[grp][30+lane]=yb; }
    __syncthreads();
    float acc = 0.f;
    for (int t=0;t<62;++t) acc += Wa_s[lane*65+1+t]*cat_s[grp][t];
    float v = lane>=1 ? acc*sc2 : 0.f;
    float res = expmap0_proj_l(v, lane);
    float r   = logmap0_l(res, lane);
    r = r>=0.f ? r : 0.2f*r;                // leaky_relu
    float res2 = expmap0_proj_l(r, lane);
    float sv   = logmap0_l(res2, lane);
    sbuf[e*32+lane] = sv;
    if (lane==0) atomicMax(&slotmap[i*NN+j], e);
}

// one block per column t=1..31: global max then sum of exp
__global__ __launch_bounds__(1024) void k_colreduce(const float* __restrict__ sbuf,
        float* __restrict__ colmax, float* __restrict__ colsum){
    int t = blockIdx.x + 1;
    __shared__ float red[1024];
    int tid = threadIdx.x;
    float mx = -3.4e38f;
    for (int e=tid; e<EE; e+=1024) mx = fmaxf(mx, sbuf[e*DD+t]);
    red[tid]=mx; __syncthreads();
    for (int off=512; off>0; off>>=1){
        if (tid<off) red[tid]=fmaxf(red[tid],red[tid+off]);
        __syncthreads();
    }
    float cm = red[0]; __syncthreads();
    float sm = 0.f;
    for (int e=tid; e<EE; e+=1024) sm += expf(sbuf[e*DD+t]-cm);
    red[tid]=sm; __syncthreads();
    for (int off=512; off>0; off>>=1){
        if (tid<off) red[tid]+=red[tid+off];
        __syncthreads();
    }
    if (tid==0){ colmax[t]=cm; colsum[t]=red[0]; }
}

// per-edge: softmax -> a = proj(expmap0([0,p])); accumulate per-cell sums
__global__ __launch_bounds__(256) void k_edge_a(const int* __restrict__ edges,
        const float* __restrict__ sbuf, const float* __restrict__ colmax,
        const float* __restrict__ colsum, const int* __restrict__ slotmap,
        float* __restrict__ asum, int* __restrict__ count){
    int tid = threadIdx.x, lane = tid&31, grp = tid>>5;
    int e = blockIdx.x*8 + grp;
    float s = sbuf[e*32+lane];
    float u = lane>=1 ? expf(s - colmax[lane])/colsum[lane] : 0.f;
    float a = expmap0_proj_l(u, lane);
    int i = edges[e], j = edges[EE+e];
    int slot = slotmap[i*NN+j];
    if (lane==0) atomicAdd(&count[slot], 1);
    atomicAdd(&asum[slot*32+lane], a);
}

// per unique cell (winner edge): att value, accumulate num/den rows
__global__ __launch_bounds__(256) void k_cell(const int* __restrict__ edges,
        const int* __restrict__ slotmap, const int* __restrict__ count,
        const float* __restrict__ asum, const float* __restrict__ in_emb,
        const float* __restrict__ lamp, float* __restrict__ numb){
    int tid = threadIdx.x, lane = tid&31, grp = tid>>5;
    int e = blockIdx.x*8 + grp;
    int i = edges[e], j = edges[EE+e];
    if (slotmap[i*NN+j] != e) return;       // group-uniform predicate
    float m  = (float)count[e];
    float ac = asum[e*32+lane];
    float w  = in_emb[j*32+lane];
    float ad = __shfl(ac,0,32)+1.f;
    float wd = m*__shfl(w,0,32)+1.f;
    float pa_ = lane>=1 ? ac/ad : 0.f;
    float pw  = lane>=1 ? m*w/wd : 0.f;
    float dot = rsum(pa_*pw);
    float wns = rsum(pw*pw);
    float wn  = sqrtf(fmaxf(wns, 1e-15f));
    float att = tanhf(dot/wn * artanh_f(wn));
    // lane 0: lamp holds lam-1 -> numb col0 is the denominator
    atomicAdd(&numb[i*32+lane], att*lamp[j*32+lane]);
}

// per-node epilogue: g -> p_out -> from_poincare -> hyp_linear(Wo, bo)
__global__ __launch_bounds__(256) void k_out(const float* __restrict__ numb,
        const float* __restrict__ Wo, const float* __restrict__ bo,
        float* __restrict__ out){
    __shared__ float Wo_s[32][33];
    int tid = threadIdx.x, lane = tid&31, grp = tid>>5;
    int i = blockIdx.x*8 + grp;
    for (int idx=tid; idx<1024; idx+=256) Wo_s[idx>>5][idx&31] = Wo[idx];
    __syncthreads();
    float nb = numb[i*32+lane];
    float dn = __shfl(nb, 0, 32);
    if (fabsf(dn) < 1e-10f) dn = 1e-10f;
    float g = lane>=1 ? nb/dn : 0.f;
    float gss = rsum(g*g);
    float gn = sqrtf(fmaxf(gss, 1e-15f));
    float scl = tanhf(0.5f*artanh_f(gn))/gn;
    g *= scl;                               // p_out
    float sq = rsum(g*g);
    float dnm = fmaxf(1.f-sq, 1e-15f);
    float h = lane==0 ? (1.f+sq)/dnm : 2.f*g/dnm;   // h_from_poincare
    float r = logmap0_l(h, lane);
    float acc = 0.f;
#pragma unroll
    for (int d=1; d<32; ++d){ float rb = __shfl(r, d, 32); acc += Wo_s[lane][d]*rb; }
    float v = lane>=1 ? acc : 0.f;
    float res = expmap0_proj_l(v, lane);
    float bt  = lane>=1 ? bo[lane] : 0.f;
    float hb  = expmap0_proj_l(bt, lane);
    float o   = mobius_add_proj_l(res, hb, lane);
    out[i*32+lane] = o;
}

extern "C" void kernel_launch(void* const* d_in, const int* in_sizes, int n_in,
                              void* d_out, int out_size, void* d_ws, size_t ws_size,
                              hipStream_t stream) {
    const float* x  = (const float*)d_in[0];
    const int* edges = (const int*)d_in[1];
    const float* Wd = (const float*)d_in[2];
    const float* bd = (const float*)d_in[3];
    const float* Wa = (const float*)d_in[4];
    const float* Wo = (const float*)d_in[5];
    const float* bo = (const float*)d_in[6];
    float* out = (float*)d_out;

    float* f       = (float*)d_ws;
    float* in_emb  = f;                      // NN*DD
    float* lamp    = in_emb + NN*DD;         // NN*DD  (col0 = lam-1)
    float* sbuf    = lamp   + NN*DD;         // EE*DD
    float* asum    = sbuf   + (size_t)EE*DD; // EE*DD
    float* numb    = asum   + (size_t)EE*DD; // NN*DD  (col0 = den)
    float* colmax  = numb   + NN*DD;         // DD
    float* colsum  = colmax + DD;            // DD
    int*   slotmap = (int*)(colsum + DD);    // NN*NN
    int*   count   = slotmap + (size_t)NN*NN;// EE

    hipMemsetAsync(slotmap, 0xFF, (size_t)NN*NN*sizeof(int), stream);   // -1
    hipMemsetAsync(asum,    0,    (size_t)EE*DD*sizeof(float), stream);
    hipMemsetAsync(count,   0,    (size_t)EE*sizeof(int), stream);
    hipMemsetAsync(numb,    0,    (size_t)NN*DD*sizeof(float), stream);

    k_node<<<NN/8, 256, 0, stream>>>(x, Wd, bd, in_emb, lamp);
    k_edge_s<<<EE/8, 256, 0, stream>>>(edges, Wa, in_emb, sbuf, slotmap);
    k_colreduce<<<DD-1, 1024, 0, stream>>>(sbuf, colmax, colsum);
    k_edge_a<<<EE/8, 256, 0, stream>>>(edges, sbuf, colmax, colsum, slotmap, asum, count);
    k_cell<<<EE/8, 256, 0, stream>>>(edges, slotmap, count, asum, in_emb, lamp, numb);
    k_out<<<NN/8, 256, 0, stream>>>(numb, Wo, bo, out);
}